// Round 18
// baseline (391.053 us; speedup 1.0000x reference)
//
#include <hip/hip_runtime.h>
#include <hip/hip_bf16.h>

// Problem constants
#define BT_TOTAL (32 * 1024)   // B*T
#define DIM 512
#define NG 8
#define NK 256
#define GD 64
#define QB 256                 // queries per block (64 per wave, 4 M-tiles)

#define XQ_ELEMS (BT_TOTAL * DIM)
#define LOSS_OFF XQ_ELEMS
#define IDX_OFF (XQ_ELEMS + 1)

typedef short s16x8 __attribute__((ext_vector_type(8)));
typedef float f32x4 __attribute__((ext_vector_type(4)));

__device__ __forceinline__ unsigned short f2bf(float f) {
    __hip_bfloat16 h = __float2bfloat16(f);
    union { __hip_bfloat16 h; unsigned short u; } cv;
    cv.h = h;
    return cv.u;
}

// ---------------------------------------------------------------------------
// Prep: canonical csq (bit-matches all prior rounds) + bf16 codebook (RNE)
// into ws. One row per thread. (r17 verbatim — proven.)
// ---------------------------------------------------------------------------
__global__ void pq_prep(const float* __restrict__ cb,
                        float* __restrict__ csq,
                        unsigned short* __restrict__ cbh,
                        float* __restrict__ loss_slot) {
    int i = blockIdx.x * 256 + threadIdx.x;  // 0 .. 2047
    if (i == 0) *loss_slot = 0.0f;
    if (i < NG * NK) {
        const float* row = cb + (size_t)i * GD;
        float a0 = 0.f, a1 = 0.f, a2 = 0.f, a3 = 0.f;
#pragma unroll
        for (int ii = 0; ii < 8; ++ii) {
            float4 vA = ((const float4*)row)[ii * 2 + 0];
            float4 vB = ((const float4*)row)[ii * 2 + 1];
            a0 = fmaf(vA.x, vA.x, a0); a1 = fmaf(vA.y, vA.y, a1);
            a2 = fmaf(vA.z, vA.z, a2); a3 = fmaf(vA.w, vA.w, a3);
            a0 = fmaf(vB.x, vB.x, a0); a1 = fmaf(vB.y, vB.y, a1);
            a2 = fmaf(vB.z, vB.z, a2); a3 = fmaf(vB.w, vB.w, a3);
            s16x8 w;
            w[0] = (short)f2bf(vA.x); w[1] = (short)f2bf(vA.y);
            w[2] = (short)f2bf(vA.z); w[3] = (short)f2bf(vA.w);
            w[4] = (short)f2bf(vB.x); w[5] = (short)f2bf(vB.y);
            w[6] = (short)f2bf(vB.z); w[7] = (short)f2bf(vB.w);
            *(s16x8*)&cbh[(size_t)i * GD + ii * 8] = w;
        }
        csq[i] = (a0 + a1) + (a2 + a3);
    }
}

// ---------------------------------------------------------------------------
// Main: 4 waves x 64 queries (4 M-tiles of 16). Two-pass MFMA screen with
// TRANSIENT accumulators (fold immediately -> no spill; pass 2 recomputes
// the deterministic MFMAs for window flagging). Guaranteed-window exact
// fp32 rescore + epilogue: r17-proven numerics verbatim.
// ---------------------------------------------------------------------------
__global__ __launch_bounds__(256, 4)
void pq_main(const float* __restrict__ x,
             const float* __restrict__ cb,
             const float* __restrict__ csq_g,
             const unsigned short* __restrict__ cbh,
             float* __restrict__ out) {
    const int g = blockIdx.y;
    const int t = threadIdx.x;
    const int lane = t & 63;
    const int wm = __builtin_amdgcn_readfirstlane(t >> 6);  // wave id
    const int lr = lane & 15, lh = lane >> 4;
    const int q0 = blockIdx.x * QB;
    const int rw = wm * 64;                 // wave's row base within block

    __shared__ float csq_l[NK];             // 1 KB
    __shared__ float absrow_l[QB];          // 1 KB
    __shared__ float sminl[QB];             // 1 KB
    __shared__ int   swinl[QB];             // 1 KB
    __shared__ int   ccount[QB];            // 1 KB
    __shared__ unsigned short cand[QB][8];  // 4 KB
    __shared__ int   m_i[QB];               // 1 KB
    __shared__ float wsum[4];

    ccount[t] = 0;
    csq_l[t] = csq_g[g * NK + t];

    // ---- A fragments for 4 M-tiles, direct from global x (+ row sum|x|) ----
    s16x8 af[4][2];
#pragma unroll
    for (int mt = 0; mt < 4; ++mt) {
        const float* xbase = x + (size_t)(q0 + rw + mt * 16 + lr) * DIM + g * GD;
        float s_abs = 0.f;
#pragma unroll
        for (int s = 0; s < 2; ++s) {
            float4 vA = *(const float4*)(xbase + s * 32 + lh * 8);
            float4 vB = *(const float4*)(xbase + s * 32 + lh * 8 + 4);
            s_abs += fabsf(vA.x) + fabsf(vA.y) + fabsf(vA.z) + fabsf(vA.w)
                   + fabsf(vB.x) + fabsf(vB.y) + fabsf(vB.z) + fabsf(vB.w);
            s16x8 w;
            w[0] = (short)f2bf(vA.x); w[1] = (short)f2bf(vA.y);
            w[2] = (short)f2bf(vA.z); w[3] = (short)f2bf(vA.w);
            w[4] = (short)f2bf(vB.x); w[5] = (short)f2bf(vB.y);
            w[6] = (short)f2bf(vB.z); w[7] = (short)f2bf(vB.w);
            af[mt][s] = w;
        }
        s_abs += __shfl_xor(s_abs, 16);
        s_abs += __shfl_xor(s_abs, 32);
        if (lh == 0) absrow_l[rw + mt * 16 + lr] = s_abs;
    }
    __syncthreads();

    // ---- pass 1: min screen; acc is TRANSIENT (fold immediately) ----
    const unsigned short* cbase = cbh + (size_t)g * NK * GD;
    float mv[4][4]; int mi[4][4];
#pragma unroll
    for (int mt = 0; mt < 4; ++mt)
#pragma unroll
        for (int r = 0; r < 4; ++r) { mv[mt][r] = 3.402823466e38f; mi[mt][r] = 0; }

#pragma unroll
    for (int n = 0; n < 16; ++n) {
        s16x8 b0 = *(const s16x8*)&cbase[(n * 16 + lr) * GD + lh * 8];
        s16x8 b1 = *(const s16x8*)&cbase[(n * 16 + lr) * GD + 32 + lh * 8];
        const float cs = csq_l[n * 16 + lr];
        const int k = n * 16 + lr;
#pragma unroll
        for (int mt = 0; mt < 4; ++mt) {
            f32x4 z = {0.f, 0.f, 0.f, 0.f};
            z = __builtin_amdgcn_mfma_f32_16x16x32_bf16(af[mt][0], b0, z, 0, 0, 0);
            z = __builtin_amdgcn_mfma_f32_16x16x32_bf16(af[mt][1], b1, z, 0, 0, 0);
#pragma unroll
            for (int r = 0; r < 4; ++r) {
                float dc = fmaf(-2.f, z[r], cs);
                if (dc < mv[mt][r]) { mv[mt][r] = dc; mi[mt][r] = k; }
            }
        }
    }
    // 16-lane lexicographic reduce (code cols live in 16 consecutive lanes)
#pragma unroll
    for (int w = 1; w < 16; w <<= 1) {
#pragma unroll
        for (int mt = 0; mt < 4; ++mt)
#pragma unroll
            for (int r = 0; r < 4; ++r) {
                float ov = __shfl_xor(mv[mt][r], w);
                int   oi = __shfl_xor(mi[mt][r], w);
                if (ov < mv[mt][r] || (ov == mv[mt][r] && oi < mi[mt][r])) {
                    mv[mt][r] = ov; mi[mt][r] = oi;
                }
            }
    }
    if (lr == 0) {
#pragma unroll
        for (int mt = 0; mt < 4; ++mt)
#pragma unroll
            for (int r = 0; r < 4; ++r) {
                sminl[rw + mt * 16 + lh * 4 + r] = mv[mt][r];
                swinl[rw + mt * 16 + lh * 4 + r] = mi[mt][r];
            }
    }
    __syncthreads();

    // ---- pass 2: recompute (deterministic) and flag the guaranteed window ----
#pragma unroll
    for (int n = 0; n < 16; ++n) {
        s16x8 b0 = *(const s16x8*)&cbase[(n * 16 + lr) * GD + lh * 8];
        s16x8 b1 = *(const s16x8*)&cbase[(n * 16 + lr) * GD + 32 + lh * 8];
        const float cs = csq_l[n * 16 + lr];
        const int k = n * 16 + lr;
#pragma unroll
        for (int mt = 0; mt < 4; ++mt) {
            f32x4 z = {0.f, 0.f, 0.f, 0.f};
            z = __builtin_amdgcn_mfma_f32_16x16x32_bf16(af[mt][0], b0, z, 0, 0, 0);
            z = __builtin_amdgcn_mfma_f32_16x16x32_bf16(af[mt][1], b1, z, 0, 0, 0);
#pragma unroll
            for (int r = 0; r < 4; ++r) {
                const int row = rw + mt * 16 + lh * 4 + r;
                const float thr = sminl[row] + (absrow_l[row] * 6.2e-5f + 1.5e-3f);
                float dc = fmaf(-2.f, z[r], cs);
                if (dc <= thr) {
                    int slot = atomicAdd(&ccount[row], 1);
                    if (slot < 8) cand[row][slot] = (unsigned short)k;
                }
            }
        }
    }
    __syncthreads();

    // ---- exact fp32 rescore: thread t handles row t (canonical numerics) ----
    {
        const int nc = ccount[t];
        int bi;
        if (nc <= 1) {
            bi = swinl[t];
        } else {
            const float* xrow = x + (size_t)(q0 + t) * DIM + g * GD;
            float xr[64];
#pragma unroll
            for (int i = 0; i < 16; ++i) {
                float4 v = ((const float4*)xrow)[i];
                xr[i * 4 + 0] = v.x; xr[i * 4 + 1] = v.y;
                xr[i * 4 + 2] = v.z; xr[i * 4 + 3] = v.w;
            }
            float a0 = 0.f, a1 = 0.f, a2 = 0.f, a3 = 0.f;
#pragma unroll
            for (int i = 0; i < 16; ++i) {
                a0 = fmaf(xr[i * 4 + 0], xr[i * 4 + 0], a0);
                a1 = fmaf(xr[i * 4 + 1], xr[i * 4 + 1], a1);
                a2 = fmaf(xr[i * 4 + 2], xr[i * 4 + 2], a2);
                a3 = fmaf(xr[i * 4 + 3], xr[i * 4 + 3], a3);
            }
            const float x_sq = (a0 + a1) + (a2 + a3);

            const bool full = nc > 8;   // astronomically rare; exact fallback
            unsigned short ks[8];
            const int mcnt = full ? 0 : nc;
            for (int i = 0; i < mcnt; ++i) ks[i] = cand[t][i];
            for (int i = 1; i < mcnt; ++i) {
                unsigned short key = ks[i];
                int j = i - 1;
                while (j >= 0 && ks[j] > key) { ks[j + 1] = ks[j]; --j; }
                ks[j + 1] = key;
            }
            float best = 3.402823466e38f; bi = 0;
            const int total = full ? NK : mcnt;
            for (int ii = 0; ii < total; ++ii) {
                const int k = full ? ii : (int)ks[ii];
                const float* ckr = cb + ((size_t)g * NK + k) * GD;
                float d0 = 0.f, d1 = 0.f, d2 = 0.f, d3 = 0.f;
#pragma unroll
                for (int i = 0; i < 16; ++i) {
                    float4 c = ((const float4*)ckr)[i];
                    d0 = fmaf(c.x, xr[i * 4 + 0], d0);
                    d1 = fmaf(c.y, xr[i * 4 + 1], d1);
                    d2 = fmaf(c.z, xr[i * 4 + 2], d2);
                    d3 = fmaf(c.w, xr[i * 4 + 3], d3);
                }
                float dot = (d0 + d1) + (d2 + d3);
                float dist = (x_sq + csq_l[k]) - 2.0f * dot;
                if (dist < best) { best = dist; bi = k; }
            }
        }
        m_i[t] = bi;
        out[IDX_OFF + (size_t)(q0 + t) * NG + g] = (float)bi;
    }
    __syncthreads();

    // ---- epilogue: coalesced x_q writes + loss partial (proven pattern) ----
    const int r_off = t >> 4;
    const int c4i = t & 15;
    float s0 = 0.f, s1 = 0.f, s2 = 0.f, s3 = 0.f;
#pragma unroll
    for (int p = 0; p < 16; ++p) {
        const int r = p * 16 + r_off;
        const int code = m_i[r];
        const size_t base = (size_t)(q0 + r) * DIM + g * GD + c4i * 4;
        float4 x4 = *(const float4*)(x + base);
        float4 q4 = *(const float4*)(cb + ((size_t)g * NK + code) * GD + c4i * 4);
        float dx = q4.x - x4.x;
        float dy = q4.y - x4.y;
        float dz = q4.z - x4.z;
        float dw = q4.w - x4.w;
        float4 o;
        o.x = x4.x + dx;
        o.y = x4.y + dy;
        o.z = x4.z + dz;
        o.w = x4.w + dw;
        *(float4*)(out + base) = o;
        s0 = fmaf(dx, dx, s0);
        s1 = fmaf(dy, dy, s1);
        s2 = fmaf(dz, dz, s2);
        s3 = fmaf(dw, dw, s3);
    }
    float part = (s0 + s1) + (s2 + s3);
#pragma unroll
    for (int off = 32; off > 0; off >>= 1) part += __shfl_down(part, off);
    if (lane == 0) wsum[wm] = part;
    __syncthreads();
    if (t == 0) {
        float bs = (wsum[0] + wsum[1]) + (wsum[2] + wsum[3]);
        atomicAdd(out + LOSS_OFF, bs * (2.0f / 2097152.0f));
    }
}

extern "C" void kernel_launch(void* const* d_in, const int* in_sizes, int n_in,
                              void* d_out, int out_size, void* d_ws, size_t ws_size,
                              hipStream_t stream) {
    const float* x = (const float*)d_in[0];
    const float* cb = (const float*)d_in[1];
    float* out = (float*)d_out;
    float* csq = (float*)d_ws;                              // 8 KB
    unsigned short* cbh = (unsigned short*)(csq + NG * NK); // 256 KB bf16 codebook

    pq_prep<<<dim3(8), dim3(256), 0, stream>>>(cb, csq, cbh, out + LOSS_OFF);

    dim3 grid(BT_TOTAL / QB, NG);   // (128, 8) = 1024 blocks
    pq_main<<<grid, dim3(256), 0, stream>>>(x, cb, csq, cbh, out);
}